// Round 9
// baseline (27.187 us; speedup 1.0000x reference)
//
#include <hip/hip_runtime.h>
#include <hip/hip_bf16.h>
#include <math.h>

#define NSENT 256
#define SLEN  512
#define VROWS 50000
#define EDIM  300
#define NROW  12
#define NSTEP 10           // ceil(300/32) K-steps of 16x16x32 MFMA
#define TROWS 64           // vocab rows per block
#define NF4   75           // float4s per row
#define TF4   (TROWS*NF4)  // 4800 float4s per tile
#define LSTR  312          // LDS row stride in bf16 elems (624B: balanced banks)

typedef __attribute__((ext_vector_type(8))) short bf16x8;
typedef __attribute__((ext_vector_type(4))) short bf16x4;
typedef __attribute__((ext_vector_type(4))) float f32x4;

static __device__ __forceinline__ short f2bf(float f) {
    __hip_bfloat16 h = __float2bfloat16(f);   // RNE
    short s;
    __builtin_memcpy(&s, &h, sizeof(s));
    return s;
}

// ---------------------------------------------------------------------------
// Kernel A: vocab scores s[v][r] = dot(emb[v], k_r) via bf16 MFMA.
// Block = 256 thr (4 waves) = 64 vocab rows; wave = one 16-row 16x16x32 tile.
// Global loads are WAVE-CONTIGUOUS (1KB/instr = 8 lines, each line fetched
// exactly once) -> kills the 64-lines/instr row-gather of rounds 6/8.
// Rows staged to LDS as bf16 (39KB; stride 312 -> fragment ds_read_b128 is
// bank-balanced 8 dwords/bank = minimum). B-frags in LDS as round 8.
// 50KB LDS -> 3 blocks/CU (round 5's fp32 version forced 1 -> serialized).
// D layout: col=lane&15 (conv row), row=(lane>>4)*4+j (m89-verified).
// ---------------------------------------------------------------------------
__global__ __launch_bounds__(256, 3)
void vocab_scores_mfma(const float* __restrict__ emb,
                       const float* __restrict__ k3,
                       const float* __restrict__ k4,
                       const float* __restrict__ k5,
                       float* __restrict__ s)
{
    __shared__ short  ebuf[TROWS * LSTR];      // 39936 B, bf16 rows
    __shared__ bf16x8 bfrag_lds[NSTEP * 64];   // 10240 B

    const int tid  = threadIdx.x;
    const int lane = tid & 63;
    const int wave = tid >> 6;      // 0..3
    const int rc   = lane & 15;     // A-row-in-tile / D-col (conv row)
    const int kg   = lane >> 4;     // k-group 0..3

    const int vbase = blockIdx.x * TROWS;
    const float4* embf4 = reinterpret_cast<const float4*>(emb);

    // ---- coalesced stage: 19 x 256 float4 covers the 64x75-f4 tile --------
    float4 pre[19];
    #pragma unroll
    for (int i = 0; i < 19; ++i) {
        const int g = i * 256 + tid;
        if (g < TF4) {
            const int row  = g / NF4;
            const int col  = g % NF4;
            const int grow = min(vbase + row, VROWS - 1);   // clamp tail
            pre[i] = embf4[(size_t)grow * NF4 + col];
        }
    }

    // ---- build B fragments cooperatively (weights tiny, L1/L2-hot) --------
    for (int e = tid; e < NSTEP * 64; e += 256) {
        const int st  = e >> 6;
        const int le  = e & 63;
        const int rce = le & 15;
        const int kge = le >> 4;
        const float* krow = nullptr;
        if      (rce < 3)  krow = k3 + rce * EDIM;
        else if (rce < 7)  krow = k4 + (rce - 3) * EDIM;
        else if (rce < 12) krow = k5 + (rce - 7) * EDIM;
        const int k0 = st * 32 + kge * 8;
        float4 b0 = make_float4(0.f,0.f,0.f,0.f);
        float4 b1 = make_float4(0.f,0.f,0.f,0.f);
        if (krow) {
            if (k0 + 4 <= EDIM) b0 = *reinterpret_cast<const float4*>(krow + k0);
            if (k0 + 8 <= EDIM) b1 = *reinterpret_cast<const float4*>(krow + k0 + 4);
        }
        bf16x8 f;
        f[0]=f2bf(b0.x); f[1]=f2bf(b0.y); f[2]=f2bf(b0.z); f[3]=f2bf(b0.w);
        f[4]=f2bf(b1.x); f[5]=f2bf(b1.y); f[6]=f2bf(b1.z); f[7]=f2bf(b1.w);
        bfrag_lds[e] = f;
    }

    // ---- convert staged tile to bf16 and write LDS (conflict-free) --------
    #pragma unroll
    for (int i = 0; i < 19; ++i) {
        const int g = i * 256 + tid;
        if (g < TF4) {
            const int row = g / NF4;
            const int col = g % NF4;
            bf16x4 w;
            w[0]=f2bf(pre[i].x); w[1]=f2bf(pre[i].y);
            w[2]=f2bf(pre[i].z); w[3]=f2bf(pre[i].w);
            *reinterpret_cast<bf16x4*>(&ebuf[row * LSTR + col * 4]) = w;
        }
    }
    __syncthreads();

    // ---- MFMA: wave's 16-row tile, A-frags straight from LDS (bf16) -------
    const int r0 = wave * 16 + rc;              // local row this lane owns
    f32x4 acc = {0.f, 0.f, 0.f, 0.f};
    #pragma unroll
    for (int st = 0; st < NSTEP; ++st) {
        const bf16x8 af = *reinterpret_cast<const bf16x8*>(
                              &ebuf[r0 * LSTR + st * 32 + kg * 8]);
        const bf16x8 bf = bfrag_lds[st * 64 + lane];
        acc = __builtin_amdgcn_mfma_f32_16x16x32_bf16(af, bf, acc, 0, 0, 0);
    }

    // store D: 4 vocab rows per lane-group (guarded tail)
    if (rc < NROW) {
        #pragma unroll
        for (int j = 0; j < 4; ++j) {
            const int v = vbase + wave * 16 + kg * 4 + j;
            if (v < VROWS) s[(size_t)v * NROW + rc] = acc[j];
        }
    }
}

// ---------------------------------------------------------------------------
// Kernel B: gather 48B/token from L2/L3-resident score table, then
// windows + tanh + max + fc + log_softmax. One block (1024 thr) per sentence.
// ---------------------------------------------------------------------------
__global__ __launch_bounds__(1024, 1)
void textcnn_finish(const int*   __restrict__ sent,
                    const float* __restrict__ s,
                    const float* __restrict__ b3,
                    const float* __restrict__ b4,
                    const float* __restrict__ b5,
                    const float* __restrict__ fcw,
                    const float* __restrict__ fcb,
                    float* __restrict__ out)
{
    __shared__ float s_lds[NROW * SLEN];
    __shared__ float red[8][3];

    const int b = blockIdx.x;
    const int t = threadIdx.x;

    auto gather = [&](int token, int j) {
        const int widx = sent[b * SLEN + token];
        const float4 v = reinterpret_cast<const float4*>(s + (size_t)widx * NROW)[j];
        s_lds[(4*j + 0) * SLEN + token] = v.x;
        s_lds[(4*j + 1) * SLEN + token] = v.y;
        s_lds[(4*j + 2) * SLEN + token] = v.z;
        s_lds[(4*j + 3) * SLEN + token] = v.w;
    };

    gather(t & 511, t >> 9);            // j = 0,1 across the 1024 threads
    if (t < SLEN) gather(t, 2);         // j = 2
    __syncthreads();

    if (t < SLEN) {
        const float bb3 = b3[0], bb4 = b4[0], bb5 = b5[0];
        float m3 = -1e30f, m4 = -1e30f, m5 = -1e30f;
        if (t < SLEN - 2)
            m3 = tanhf(s_lds[0*SLEN + t] + s_lds[1*SLEN + t+1] +
                       s_lds[2*SLEN + t+2] + bb3);
        if (t < SLEN - 3)
            m4 = tanhf(s_lds[3*SLEN + t] + s_lds[4*SLEN + t+1] +
                       s_lds[5*SLEN + t+2] + s_lds[6*SLEN + t+3] + bb4);
        if (t < SLEN - 4)
            m5 = tanhf(s_lds[7*SLEN + t] + s_lds[8*SLEN + t+1] +
                       s_lds[9*SLEN + t+2] + s_lds[10*SLEN + t+3] +
                       s_lds[11*SLEN + t+4] + bb5);

        #pragma unroll
        for (int off = 32; off; off >>= 1) {
            m3 = fmaxf(m3, __shfl_xor(m3, off));
            m4 = fmaxf(m4, __shfl_xor(m4, off));
            m5 = fmaxf(m5, __shfl_xor(m5, off));
        }
        if ((t & 63) == 0) {
            const int w = t >> 6;
            red[w][0] = m3; red[w][1] = m4; red[w][2] = m5;
        }
    }
    __syncthreads();

    if (t == 0) {
        float f3 = red[0][0], f4 = red[0][1], f5 = red[0][2];
        #pragma unroll
        for (int w = 1; w < 8; ++w) {
            f3 = fmaxf(f3, red[w][0]);
            f4 = fmaxf(f4, red[w][1]);
            f5 = fmaxf(f5, red[w][2]);
        }
        float lg[10];
        float mx = -1e30f;
        #pragma unroll
        for (int c = 0; c < 10; ++c) {
            lg[c] = fcb[c] + f3 * fcw[c*3+0] + f4 * fcw[c*3+1] + f5 * fcw[c*3+2];
            mx = fmaxf(mx, lg[c]);
        }
        float ssum = 0.f;
        #pragma unroll
        for (int c = 0; c < 10; ++c) ssum += expf(lg[c] - mx);
        const float lse = logf(ssum);
        #pragma unroll
        for (int c = 0; c < 10; ++c) out[b * 10 + c] = lg[c] - mx - lse;
    }
}

extern "C" void kernel_launch(void* const* d_in, const int* in_sizes, int n_in,
                              void* d_out, int out_size, void* d_ws, size_t ws_size,
                              hipStream_t stream) {
    const int*   sent = (const int*)  d_in[0];
    const float* emb  = (const float*)d_in[1];
    const float* k3   = (const float*)d_in[2];
    const float* b3   = (const float*)d_in[3];
    const float* k4   = (const float*)d_in[4];
    const float* b4   = (const float*)d_in[5];
    const float* k5   = (const float*)d_in[6];
    const float* b5   = (const float*)d_in[7];
    const float* fcw  = (const float*)d_in[8];
    const float* fcb  = (const float*)d_in[9];
    float* out = (float*)d_out;
    float* s   = (float*)d_ws;        // VROWS * 12 * 4 B = 2.4 MB

    const int nblk = (VROWS + TROWS - 1) / TROWS;   // 782
    vocab_scores_mfma<<<nblk, 256, 0, stream>>>(emb, k3, k4, k5, s);
    textcnn_finish<<<NSENT, 1024, 0, stream>>>(sent, s, b3, b4, b5, fcw, fcb, out);
}